// Round 4
// baseline (252.702 us; speedup 1.0000x reference)
//
#include <hip/hip_runtime.h>
#include <hip/hip_bf16.h>
#include <math.h>

#define INDIM 768
#define NROWS 32768       // 8*4096
#define KSEL  38
#define NCOLS 76
#define HID   256
#define LN_EPS 1e-5f

typedef float  f32x4  __attribute__((ext_vector_type(4)));
typedef __bf16 bf16x8 __attribute__((ext_vector_type(8)));

#define MFMA16(a,b,c) __builtin_amdgcn_mfma_f32_16x16x32_bf16((a),(b),(c),0,0,0)

// ---- workspace: shared matrices pre-packed in MFMA B-fragment order ----
// frag value(lane, j) = M[n = nt*16 + (lane&15)][k = ks*32 + (lane>>4)*8 + j]
// BfP: DFT basis,  frag = kc*5 + nt   (kc 0..23, nt 0..4)   : 120 frags
// W1P: layer1 w,   frag = mlp*48 + nt*3 + ks (nt 0..15)     : 96 frags
// W2P: layer2 w,   frag = mlp*40 + nt*8 + ks (nt 0..4)      : 80 frags
// BsP: synth basis frag = nt*3 + ks  (nt 0..47)             : 144 frags
// Z1:  x_in  (DFT out)  bf16 [NROWS][96]  (cols 76..95 zero)
// Z2:  z = mu+eps*sg    bf16 [NROWS][96]  (cols 76..95 zero)
#define OFF_BFP 0
#define OFF_W1P 122880
#define OFF_W2P 221184
#define OFF_BSP 303104
#define OFF_Z1  450560
#define OFF_Z2  6742016

__global__ void k_prep(const int* __restrict__ idxs,
                       const float* __restrict__ mu_w1, const float* __restrict__ sg_w1,
                       const float* __restrict__ mu_w2, const float* __restrict__ sg_w2,
                       __bf16* __restrict__ BfP, __bf16* __restrict__ W1P,
                       __bf16* __restrict__ W2P, __bf16* __restrict__ BsP)
{
    int tid = blockIdx.x * blockDim.x + threadIdx.x;
    int nth = gridDim.x * blockDim.x;
    const float TH = 6.28318530717958647692f / (float)INDIM;

    for (int e = tid; e < 120 * 512; e += nth) {
        int frag = e >> 9, lane = (e >> 3) & 63, j = e & 7;
        int kc = frag / 5, nt = frag % 5;
        int c = nt * 16 + (lane & 15);
        int k = kc * 32 + ((lane >> 4) << 3) + j;
        float v = 0.f;
        if (c < NCOLS) {
            int cc = (c < KSEL) ? c : c - KSEL;
            int f = idxs[cc];
            int m = (f * k) % INDIM;
            float s, co; sincosf(TH * (float)m, &s, &co);
            v = (c < KSEL) ? co : -s;
        }
        BfP[e] = (__bf16)v;
    }
    for (int e = tid; e < 96 * 512; e += nth) {
        int frag = e >> 9, lane = (e >> 3) & 63, j = e & 7;
        int mlp = frag / 48; int r = frag % 48;
        int nt = r / 3, ks = r % 3;
        int row = nt * 16 + (lane & 15);
        int k = ks * 32 + ((lane >> 4) << 3) + j;
        const float* W = mlp ? sg_w1 : mu_w1;
        W1P[e] = (__bf16)((k < NCOLS) ? W[row * NCOLS + k] : 0.f);
    }
    for (int e = tid; e < 80 * 512; e += nth) {
        int frag = e >> 9, lane = (e >> 3) & 63, j = e & 7;
        int mlp = frag / 40; int r = frag % 40;
        int nt = r / 8, ks = r % 8;
        int row = nt * 16 + (lane & 15);
        int k = ks * 32 + ((lane >> 4) << 3) + j;
        const float* W = mlp ? sg_w2 : mu_w2;
        W2P[e] = (__bf16)((row < NCOLS) ? W[row * HID + k] : 0.f);
    }
    for (int e = tid; e < 144 * 512; e += nth) {
        int frag = e >> 9, lane = (e >> 3) & 63, j = e & 7;
        int nt = frag / 3, ks = frag % 3;
        int n = nt * 16 + (lane & 15);
        int k = ks * 32 + ((lane >> 4) << 3) + j;
        float v = 0.f;
        if (k < NCOLS) {
            int cc = (k < KSEL) ? k : k - KSEL;
            int f = idxs[cc];
            int m = (f * n) % INDIM;
            float s, co; sincosf(TH * (float)m, &s, &co);
            v = ((k < KSEL) ? co : -s) * (2.0f / (float)INDIM);
        }
        BsP[e] = (__bf16)v;
    }
}

// tanh-form gelu (error vs exact ~3e-4 on gelu out -> ~5e-6 on final out)
static __device__ inline float gelu_fast(float v) {
    float u = v * (0.79788456080286535588f + 0.03567740813636141f * v * v);
    return v / (1.f + __expf(-2.f * u));
}

// ============================ K1: DFT =====================================
// z1[r][0..79] = x[r][:] @ Bf^T  (cols 76..79 natural zeros via packed Bf),
// cols 80..95 explicit zeros. K-split-4: wave w takes K-slice [w*192,w*192+192);
// fp32 partials combined via LDS. 256 thr = 4 waves = 1 row tile, grid 2048.
// B-frags read straight from L2 (no LDS staging, no vmcnt drains).
// Reg budget <=64 (launch_bounds min 8 waves/EU) -> 8 waves/SIMD latency hiding.
__global__ __launch_bounds__(256, 8) void k_dft(
    const float* __restrict__ x, const __bf16* __restrict__ Bf,
    __bf16* __restrict__ z1)
{
    __shared__ __align__(16) float PA[3][1280];
    int tid = threadIdx.x;
    int w = tid >> 6, lane = tid & 63, q = lane >> 4, l16 = lane & 15;
    int rbase = blockIdx.x * 16;

    f32x4 acc[5] = {};
    const float* xrow = x + (size_t)(rbase + l16) * INDIM + w * 192 + q * 8;
    const __bf16* bfb = Bf + (size_t)(w * 30) * 512 + (size_t)lane * 8;
    #pragma unroll
    for (int kk = 0; kk < 6; ++kk) {
        float4 f0 = ((const float4*)(xrow + kk * 32))[0];
        float4 f1 = ((const float4*)(xrow + kk * 32))[1];
        union { __bf16 h[8]; bf16x8 v; } a;
        a.h[0]=(__bf16)f0.x; a.h[1]=(__bf16)f0.y; a.h[2]=(__bf16)f0.z; a.h[3]=(__bf16)f0.w;
        a.h[4]=(__bf16)f1.x; a.h[5]=(__bf16)f1.y; a.h[6]=(__bf16)f1.z; a.h[7]=(__bf16)f1.w;
        #pragma unroll
        for (int nt = 0; nt < 5; ++nt) {
            bf16x8 b = *(const bf16x8*)(bfb + (size_t)(kk * 5 + nt) * 512);
            acc[nt] = MFMA16(a.v, b, acc[nt]);
        }
    }
    if (w > 0) {
        #pragma unroll
        for (int nt = 0; nt < 5; ++nt)
            #pragma unroll
            for (int r = 0; r < 4; ++r)
                PA[w - 1][(q * 4 + r) * 80 + nt * 16 + l16] = acc[nt][r];
    }
    __syncthreads();
    if (w == 0) {
        #pragma unroll
        for (int nt = 0; nt < 5; ++nt)
            #pragma unroll
            for (int r = 0; r < 4; ++r) {
                int i = (q * 4 + r) * 80 + nt * 16 + l16;
                float v = acc[nt][r] + PA[0][i] + PA[1][i] + PA[2][i];
                z1[(size_t)(rbase + q * 4 + r) * 96 + nt * 16 + l16] = (__bf16)v;
            }
        #pragma unroll
        for (int r = 0; r < 4; ++r)
            ((unsigned short*)z1)[(size_t)(rbase + q * 4 + r) * 96 + 80 + l16] = 0;
    }
}

// ============================ K2: MLP + z ==================================
// Pair-split as before (p=0 mu, p=1 sg), 256 thr = 4 waves = 2 tiles,
// grid 1024. A-frags from z1 (L2-hot), W1/W2 B-frags from L2 directly.
// One barrier total (mu->sg exchange). LDS = PA 10K + GW 17K = 27 KB.
__global__ __launch_bounds__(256, 4) void k_mlp(
    const __bf16* __restrict__ z1, const float* __restrict__ eps,
    const __bf16* __restrict__ W1f, const __bf16* __restrict__ W2f,
    const float* __restrict__ mu_b1, const float* __restrict__ mu_g,
    const float* __restrict__ mu_be, const float* __restrict__ mu_b2,
    const float* __restrict__ sg_b1, const float* __restrict__ sg_g,
    const float* __restrict__ sg_be, const float* __restrict__ sg_b2,
    __bf16* __restrict__ z2)
{
    __shared__ __align__(16) float  PA[2][1280];
    __shared__ __align__(16) __bf16 GW[4][2176];
    int tid = threadIdx.x;
    int w = tid >> 6, lane = tid & 63, q = lane >> 4, l16 = lane & 15;
    int t = w >> 1, p = w & 1;
    int rbase = blockIdx.x * 32 + t * 16;

    bf16x8 a1[3];
    #pragma unroll
    for (int ks = 0; ks < 3; ++ks)
        a1[ks] = *(const bf16x8*)(z1 + (size_t)(rbase + l16) * 96 + ks * 32 + q * 8);

    const float* b1 = p ? sg_b1 : mu_b1;
    const float* g  = p ? sg_g  : mu_g;
    const float* be = p ? sg_be : mu_be;

    // layer 1
    const __bf16* w1b = W1f + (size_t)(p * 48) * 512 + (size_t)lane * 8;
    f32x4 h[16] = {};
    #pragma unroll
    for (int nt = 0; nt < 16; ++nt)
        #pragma unroll
        for (int ks = 0; ks < 3; ++ks) {
            bf16x8 b = *(const bf16x8*)(w1b + (size_t)(nt * 3 + ks) * 512);
            h[nt] = MFMA16(a1[ks], b, h[nt]);
        }
    float s[4] = {}, ss[4] = {};
    #pragma unroll
    for (int nt = 0; nt < 16; ++nt) {
        float bb = b1[nt * 16 + l16];
        #pragma unroll
        for (int r = 0; r < 4; ++r) {
            float v = h[nt][r] + bb; h[nt][r] = v;
            s[r] += v; ss[r] += v * v;
        }
    }
    #pragma unroll
    for (int off = 1; off < 16; off <<= 1)
        #pragma unroll
        for (int r = 0; r < 4; ++r) {
            s[r] += __shfl_xor(s[r], off); ss[r] += __shfl_xor(ss[r], off);
        }
    float mean[4], rstd[4];
    #pragma unroll
    for (int r = 0; r < 4; ++r) {
        mean[r] = s[r] * (1.f / 256.f);
        rstd[r] = rsqrtf(ss[r] * (1.f / 256.f) - mean[r] * mean[r] + LN_EPS);
    }
    // LN + gelu -> wave-private LDS buffer (stride 136), then A2 frags
    __bf16* gw = &GW[w][0];
    bf16x8 a2[8];
    #pragma unroll
    for (int half = 0; half < 2; ++half) {
        #pragma unroll
        for (int ntl = 0; ntl < 8; ++ntl) {
            int nt = half * 8 + ntl;
            int i = nt * 16 + l16;
            float gv = g[i], bev = be[i];
            #pragma unroll
            for (int r = 0; r < 4; ++r)
                gw[(q * 4 + r) * 136 + ntl * 16 + l16] =
                    (__bf16)gelu_fast((h[nt][r] - mean[r]) * rstd[r] * gv + bev);
        }
        #pragma unroll
        for (int ks = 0; ks < 4; ++ks)
            a2[half * 4 + ks] = *(const bf16x8*)&gw[l16 * 136 + ks * 32 + q * 8];
    }
    // layer 2
    const __bf16* w2b = W2f + (size_t)(p * 40) * 512 + (size_t)lane * 8;
    f32x4 o[5] = {};
    #pragma unroll
    for (int nt = 0; nt < 5; ++nt)
        #pragma unroll
        for (int ks = 0; ks < 8; ++ks) {
            bf16x8 b = *(const bf16x8*)(w2b + (size_t)(nt * 8 + ks) * 512);
            o[nt] = MFMA16(a2[ks], b, o[nt]);
        }
    // z = (mu+b2m) + eps*(sg+b2s)
    float ev[5][4];
    if (p == 0) {
        #pragma unroll
        for (int nt = 0; nt < 5; ++nt)
            #pragma unroll
            for (int r = 0; r < 4; ++r)
                PA[t][(q * 4 + r) * 80 + nt * 16 + l16] = o[nt][r];
    } else {
        #pragma unroll
        for (int nt = 0; nt < 5; ++nt) {
            int j = nt * 16 + l16;
            #pragma unroll
            for (int r = 0; r < 4; ++r)
                ev[nt][r] = (j < NCOLS)
                    ? eps[(size_t)(rbase + q * 4 + r) * NCOLS + j] : 0.f;
        }
    }
    __syncthreads();
    if (p == 1) {
        #pragma unroll
        for (int nt = 0; nt < 5; ++nt) {
            int j = nt * 16 + l16;
            float b2m = (j < NCOLS) ? mu_b2[j] : 0.f;
            float b2s = (j < NCOLS) ? sg_b2[j] : 0.f;
            #pragma unroll
            for (int r = 0; r < 4; ++r) {
                float z = 0.f;
                if (j < NCOLS) {
                    float omu = PA[t][(q * 4 + r) * 80 + j];
                    z = (omu + b2m) + ev[nt][r] * (o[nt][r] + b2s);
                }
                z2[(size_t)(rbase + q * 4 + r) * 96 + j] = (__bf16)z;
            }
        }
        #pragma unroll
        for (int r = 0; r < 4; ++r)
            ((unsigned short*)z2)[(size_t)(rbase + q * 4 + r) * 96 + 80 + l16] = 0;
    }
}

// ============================ K3: synthesis ================================
// out = z2 @ Bs. N-split-4: wave w covers n-tiles [w*12, w*12+12).
// 256 thr = 4 waves = 1 row tile, grid 2048. Zero LDS, zero barriers,
// ~40 regs -> 8 waves/SIMD; write-bound streaming.
__global__ __launch_bounds__(256, 8) void k_syn(
    const __bf16* __restrict__ z2, const __bf16* __restrict__ Bs,
    float* __restrict__ out)
{
    int tid = threadIdx.x;
    int w = tid >> 6, lane = tid & 63, q = lane >> 4, l16 = lane & 15;
    int rbase = blockIdx.x * 16;

    bf16x8 az[3];
    #pragma unroll
    for (int ks = 0; ks < 3; ++ks)
        az[ks] = *(const bf16x8*)(z2 + (size_t)(rbase + l16) * 96 + ks * 32 + q * 8);

    const __bf16* bsb = Bs + (size_t)(w * 36) * 512 + (size_t)lane * 8;
    #pragma unroll 4
    for (int ntl = 0; ntl < 12; ++ntl) {
        f32x4 oc = {};
        #pragma unroll
        for (int ks = 0; ks < 3; ++ks) {
            bf16x8 b = *(const bf16x8*)(bsb + (size_t)(ntl * 3 + ks) * 512);
            oc = MFMA16(az[ks], b, oc);
        }
        #pragma unroll
        for (int r = 0; r < 4; ++r)
            out[(size_t)(rbase + q * 4 + r) * INDIM + w * 192 + ntl * 16 + l16] = oc[r];
    }
}

extern "C" void kernel_launch(void* const* d_in, const int* in_sizes, int n_in,
                              void* d_out, int out_size, void* d_ws, size_t ws_size,
                              hipStream_t stream)
{
    const float* x     = (const float*)d_in[0];
    const float* eps   = (const float*)d_in[1];
    const int*   idxs  = (const int*)  d_in[2];
    const float* mu_w1 = (const float*)d_in[3];
    const float* mu_b1 = (const float*)d_in[4];
    const float* mu_g  = (const float*)d_in[5];
    const float* mu_be = (const float*)d_in[6];
    const float* mu_w2 = (const float*)d_in[7];
    const float* mu_b2 = (const float*)d_in[8];
    const float* sg_w1 = (const float*)d_in[9];
    const float* sg_b1 = (const float*)d_in[10];
    const float* sg_g  = (const float*)d_in[11];
    const float* sg_be = (const float*)d_in[12];
    const float* sg_w2 = (const float*)d_in[13];
    const float* sg_b2 = (const float*)d_in[14];
    float* out = (float*)d_out;

    char* ws = (char*)d_ws;
    __bf16* BfP = (__bf16*)(ws + OFF_BFP);
    __bf16* W1P = (__bf16*)(ws + OFF_W1P);
    __bf16* W2P = (__bf16*)(ws + OFF_W2P);
    __bf16* BsP = (__bf16*)(ws + OFF_BSP);
    __bf16* Z1  = (__bf16*)(ws + OFF_Z1);
    __bf16* Z2  = (__bf16*)(ws + OFF_Z2);

    hipLaunchKernelGGL(k_prep, dim3(1024), dim3(256), 0, stream,
                       idxs, mu_w1, sg_w1, mu_w2, sg_w2, BfP, W1P, W2P, BsP);
    hipLaunchKernelGGL(k_dft, dim3(NROWS / 16), dim3(256), 0, stream,
                       x, BfP, Z1);
    hipLaunchKernelGGL(k_mlp, dim3(NROWS / 32), dim3(256), 0, stream,
                       Z1, eps, W1P, W2P,
                       mu_b1, mu_g, mu_be, mu_b2,
                       sg_b1, sg_g, sg_be, sg_b2, Z2);
    hipLaunchKernelGGL(k_syn, dim3(NROWS / 16), dim3(256), 0, stream,
                       Z2, BsP, out);
}

// Round 5
// 248.460 us; speedup vs baseline: 1.0171x; 1.0171x over previous
//
#include <hip/hip_runtime.h>
#include <hip/hip_bf16.h>
#include <math.h>

#define INDIM 768
#define NROWS 32768       // 8*4096
#define KSEL  38
#define NCOLS 76
#define HID   256
#define LN_EPS 1e-5f

typedef float  f32x4  __attribute__((ext_vector_type(4)));
typedef __bf16 bf16x8 __attribute__((ext_vector_type(8)));

#define MFMA16(a,b,c) __builtin_amdgcn_mfma_f32_16x16x32_bf16((a),(b),(c),0,0,0)

// ---- workspace: shared matrices pre-packed in MFMA B-fragment order ----
// frag value(lane, j) = M[n = nt*16 + (lane&15)][k = ks*32 + (lane>>4)*8 + j]
// BfP: DFT basis,  frag = kc*6 + nt  (kc 0..23, nt 0..5, 96-col) : 144 frags
// W1P: layer1 w,   frag = mlp*48 + nt*3 + ks (nt 0..15)          : 96 frags
// W2P: layer2 w,   frag = mlp*40 + nt*8 + ks (nt 0..4)           : 80 frags
// BsP: synth basis frag = nt*3 + ks  (nt 0..47)                  : 144 frags
// Z1:  x_in (DFT out) bf16 [NROWS][96] (cols 76..95 zero)
// Z2:  z = mu+eps*sg  bf16 [NROWS][96] (cols 76..95 zero)
#define OFF_BFP 0
#define OFF_W1P 147456
#define OFF_W2P 245760
#define OFF_BSP 327680
#define OFF_Z1  475136
#define OFF_Z2  6766592

__global__ void k_prep(const int* __restrict__ idxs,
                       const float* __restrict__ mu_w1, const float* __restrict__ sg_w1,
                       const float* __restrict__ mu_w2, const float* __restrict__ sg_w2,
                       __bf16* __restrict__ BfP, __bf16* __restrict__ W1P,
                       __bf16* __restrict__ W2P, __bf16* __restrict__ BsP)
{
    int tid = blockIdx.x * blockDim.x + threadIdx.x;
    int nth = gridDim.x * blockDim.x;
    const float TH = 6.28318530717958647692f / (float)INDIM;

    for (int e = tid; e < 144 * 512; e += nth) {     // 96-col DFT basis
        int frag = e >> 9, lane = (e >> 3) & 63, j = e & 7;
        int kc = frag / 6, nt = frag % 6;
        int c = nt * 16 + (lane & 15);
        int k = kc * 32 + ((lane >> 4) << 3) + j;
        float v = 0.f;
        if (c < NCOLS) {
            int cc = (c < KSEL) ? c : c - KSEL;
            int f = idxs[cc];
            int m = (f * k) % INDIM;
            float s, co; sincosf(TH * (float)m, &s, &co);
            v = (c < KSEL) ? co : -s;
        }
        BfP[e] = (__bf16)v;
    }
    for (int e = tid; e < 96 * 512; e += nth) {
        int frag = e >> 9, lane = (e >> 3) & 63, j = e & 7;
        int mlp = frag / 48; int r = frag % 48;
        int nt = r / 3, ks = r % 3;
        int row = nt * 16 + (lane & 15);
        int k = ks * 32 + ((lane >> 4) << 3) + j;
        const float* W = mlp ? sg_w1 : mu_w1;
        W1P[e] = (__bf16)((k < NCOLS) ? W[row * NCOLS + k] : 0.f);
    }
    for (int e = tid; e < 80 * 512; e += nth) {
        int frag = e >> 9, lane = (e >> 3) & 63, j = e & 7;
        int mlp = frag / 40; int r = frag % 40;
        int nt = r / 8, ks = r % 8;
        int row = nt * 16 + (lane & 15);
        int k = ks * 32 + ((lane >> 4) << 3) + j;
        const float* W = mlp ? sg_w2 : mu_w2;
        W2P[e] = (__bf16)((row < NCOLS) ? W[row * HID + k] : 0.f);
    }
    for (int e = tid; e < 144 * 512; e += nth) {
        int frag = e >> 9, lane = (e >> 3) & 63, j = e & 7;
        int nt = frag / 3, ks = frag % 3;
        int n = nt * 16 + (lane & 15);
        int k = ks * 32 + ((lane >> 4) << 3) + j;
        float v = 0.f;
        if (k < NCOLS) {
            int cc = (k < KSEL) ? k : k - KSEL;
            int f = idxs[cc];
            int m = (f * n) % INDIM;
            float s, co; sincosf(TH * (float)m, &s, &co);
            v = ((k < KSEL) ? co : -s) * (2.0f / (float)INDIM);
        }
        BsP[e] = (__bf16)v;
    }
}

// tanh-form gelu (error vs exact ~3e-4 on gelu out -> ~5e-6 on final out)
static __device__ inline float gelu_fast(float v) {
    float u = v * (0.79788456080286535588f + 0.03567740813636141f * v * v);
    return v / (1.f + __expf(-2.f * u));
}

typedef __attribute__((address_space(1))) const unsigned int g_u32;
typedef __attribute__((address_space(3))) unsigned int l_u32;

// ============================ K1: DFT =====================================
// z1[r][0..95] = x[r][:] @ Bf^T (96-col packed basis; cols >=76 zero tiles).
// 512 thr = 8 waves = 4 row-tiles x 2 nt-halves; 64 rows/block; grid 512
// -> 2 independent blocks/CU (LDS 28 KB, regs <=64) so chunk-barrier tails
// counter-phase across blocks.
// Per kk (24 iters of K=32): x-slice (64 rows x 32 f32 = 8 KB) and Bf chunk
// (6 KB) double-buffered via global_load_lds (zero-VGPR deep queue -- beats
// the ~50 GB/s/CU VGPR-load latency ceiling that bound R0-R4).
// x-slice is stored XOR-swizzled via pre-swizzled SOURCE address (linear
// LDS dst, rule: inverse-swz source + swz read) -> conflict-free f32 reads.
__global__ __launch_bounds__(512, 8) void k_dft(
    const float* __restrict__ x, const __bf16* __restrict__ Bf,
    __bf16* __restrict__ z1)
{
    __shared__ __align__(16) char R[28672];   // Xs[2][8K] @0, Bq[2][6K] @16384
    int tid = threadIdx.x;
    int w = tid >> 6, lane = tid & 63, q = lane >> 4, l16 = lane & 15;
    int t = w >> 1, g = w & 1;
    int rbase = blockIdx.x * 64;

    // per-wave staging source lanes (computed once)
    int xrow_u = (lane >> 3);                 // row within 8-row unit
    int xcol_f = ((lane & 7) ^ xrow_u) << 2;  // swizzled float offset in window

    f32x4 acc[3] = {};
    // prologue: stage chunk 0
    {
        const float* sx = x + (size_t)(rbase + w * 8 + xrow_u) * INDIM + xcol_f;
        __builtin_amdgcn_global_load_lds((g_u32*)sx, (l_u32*)(R + w * 1024), 16, 0, 0);
        if (w < 6)
            __builtin_amdgcn_global_load_lds(
                (g_u32*)(Bf + (size_t)w * 512 + lane * 8),
                (l_u32*)(R + 16384 + w * 1024), 16, 0, 0);
    }
    __syncthreads();

    for (int kk = 0; kk < 24; ++kk) {
        int buf = kk & 1;
        if (kk < 23) {   // stage chunk kk+1 into buf^1 (issued before compute)
            const float* sx = x + (size_t)(rbase + w * 8 + xrow_u) * INDIM
                                + (kk + 1) * 32 + xcol_f;
            __builtin_amdgcn_global_load_lds((g_u32*)sx,
                (l_u32*)(R + (buf ^ 1) * 8192 + w * 1024), 16, 0, 0);
            if (w < 6)
                __builtin_amdgcn_global_load_lds(
                    (g_u32*)(Bf + (size_t)((kk + 1) * 6 + w) * 512 + lane * 8),
                    (l_u32*)(R + 16384 + (buf ^ 1) * 6144 + w * 1024), 16, 0, 0);
        }
        // A-frag: row t*16+l16, k-window floats q*8..q*8+8 (swizzled read)
        const char* xb = R + buf * 8192 + (t * 16 + l16) * 128;
        int s = (l16 & 7) << 4;
        f32x4 f0 = *(const f32x4*)(xb + ((q * 32) ^ s));
        f32x4 f1 = *(const f32x4*)(xb + (((q * 32) + 16) ^ s));
        union { __bf16 h[8]; bf16x8 v; } a;
        a.h[0]=(__bf16)f0[0]; a.h[1]=(__bf16)f0[1]; a.h[2]=(__bf16)f0[2]; a.h[3]=(__bf16)f0[3];
        a.h[4]=(__bf16)f1[0]; a.h[5]=(__bf16)f1[1]; a.h[6]=(__bf16)f1[2]; a.h[7]=(__bf16)f1[3];
        const char* bb = R + 16384 + buf * 6144 + g * 3072 + (size_t)lane * 16;
        #pragma unroll
        for (int ntl = 0; ntl < 3; ++ntl) {
            bf16x8 b = *(const bf16x8*)(bb + ntl * 1024);
            acc[ntl] = MFMA16(a.v, b, acc[ntl]);
        }
        __syncthreads();   // chunk kk consumed; chunk kk+1 staged+drained
    }
    // C-write: col = l16, row = q*4+r; z1 cols 76..95 are zeros via Bf packing
    #pragma unroll
    for (int ntl = 0; ntl < 3; ++ntl)
        #pragma unroll
        for (int r = 0; r < 4; ++r)
            z1[(size_t)(rbase + t * 16 + q * 4 + r) * 96 + g * 48 + ntl * 16 + l16]
                = (__bf16)acc[ntl][r];
}

// ============================ K2: MLP + z ==================================
// Pair-split (p=0 mu, p=1 sg), 256 thr = 4 waves = 2 tiles, grid 1024.
// A-frags from z1 (L2-hot), W1/W2 B-frags from L2 directly.
__global__ __launch_bounds__(256, 4) void k_mlp(
    const __bf16* __restrict__ z1, const float* __restrict__ eps,
    const __bf16* __restrict__ W1f, const __bf16* __restrict__ W2f,
    const float* __restrict__ mu_b1, const float* __restrict__ mu_g,
    const float* __restrict__ mu_be, const float* __restrict__ mu_b2,
    const float* __restrict__ sg_b1, const float* __restrict__ sg_g,
    const float* __restrict__ sg_be, const float* __restrict__ sg_b2,
    __bf16* __restrict__ z2)
{
    __shared__ __align__(16) float  PA[2][1280];
    __shared__ __align__(16) __bf16 GW[4][2176];
    int tid = threadIdx.x;
    int w = tid >> 6, lane = tid & 63, q = lane >> 4, l16 = lane & 15;
    int t = w >> 1, p = w & 1;
    int rbase = blockIdx.x * 32 + t * 16;

    bf16x8 a1[3];
    #pragma unroll
    for (int ks = 0; ks < 3; ++ks)
        a1[ks] = *(const bf16x8*)(z1 + (size_t)(rbase + l16) * 96 + ks * 32 + q * 8);

    const float* b1 = p ? sg_b1 : mu_b1;
    const float* g  = p ? sg_g  : mu_g;
    const float* be = p ? sg_be : mu_be;

    // layer 1
    const __bf16* w1b = W1f + (size_t)(p * 48) * 512 + (size_t)lane * 8;
    f32x4 h[16] = {};
    #pragma unroll
    for (int nt = 0; nt < 16; ++nt)
        #pragma unroll
        for (int ks = 0; ks < 3; ++ks) {
            bf16x8 b = *(const bf16x8*)(w1b + (size_t)(nt * 3 + ks) * 512);
            h[nt] = MFMA16(a1[ks], b, h[nt]);
        }
    float s[4] = {}, ss[4] = {};
    #pragma unroll
    for (int nt = 0; nt < 16; ++nt) {
        float bb = b1[nt * 16 + l16];
        #pragma unroll
        for (int r = 0; r < 4; ++r) {
            float v = h[nt][r] + bb; h[nt][r] = v;
            s[r] += v; ss[r] += v * v;
        }
    }
    #pragma unroll
    for (int off = 1; off < 16; off <<= 1)
        #pragma unroll
        for (int r = 0; r < 4; ++r) {
            s[r] += __shfl_xor(s[r], off); ss[r] += __shfl_xor(ss[r], off);
        }
    float mean[4], rstd[4];
    #pragma unroll
    for (int r = 0; r < 4; ++r) {
        mean[r] = s[r] * (1.f / 256.f);
        rstd[r] = rsqrtf(ss[r] * (1.f / 256.f) - mean[r] * mean[r] + LN_EPS);
    }
    // LN + gelu -> wave-private LDS buffer (stride 136), then A2 frags
    __bf16* gw = &GW[w][0];
    bf16x8 a2[8];
    #pragma unroll
    for (int half = 0; half < 2; ++half) {
        #pragma unroll
        for (int ntl = 0; ntl < 8; ++ntl) {
            int nt = half * 8 + ntl;
            int i = nt * 16 + l16;
            float gv = g[i], bev = be[i];
            #pragma unroll
            for (int r = 0; r < 4; ++r)
                gw[(q * 4 + r) * 136 + ntl * 16 + l16] =
                    (__bf16)gelu_fast((h[nt][r] - mean[r]) * rstd[r] * gv + bev);
        }
        #pragma unroll
        for (int ks = 0; ks < 4; ++ks)
            a2[half * 4 + ks] = *(const bf16x8*)&gw[l16 * 136 + ks * 32 + q * 8];
    }
    // layer 2
    const __bf16* w2b = W2f + (size_t)(p * 40) * 512 + (size_t)lane * 8;
    f32x4 o[5] = {};
    #pragma unroll
    for (int nt = 0; nt < 5; ++nt)
        #pragma unroll
        for (int ks = 0; ks < 8; ++ks) {
            bf16x8 b = *(const bf16x8*)(w2b + (size_t)(nt * 8 + ks) * 512);
            o[nt] = MFMA16(a2[ks], b, o[nt]);
        }
    // z = (mu+b2m) + eps*(sg+b2s)
    float ev[5][4];
    if (p == 0) {
        #pragma unroll
        for (int nt = 0; nt < 5; ++nt)
            #pragma unroll
            for (int r = 0; r < 4; ++r)
                PA[t][(q * 4 + r) * 80 + nt * 16 + l16] = o[nt][r];
    } else {
        #pragma unroll
        for (int nt = 0; nt < 5; ++nt) {
            int j = nt * 16 + l16;
            #pragma unroll
            for (int r = 0; r < 4; ++r)
                ev[nt][r] = (j < NCOLS)
                    ? eps[(size_t)(rbase + q * 4 + r) * NCOLS + j] : 0.f;
        }
    }
    __syncthreads();
    if (p == 1) {
        #pragma unroll
        for (int nt = 0; nt < 5; ++nt) {
            int j = nt * 16 + l16;
            float b2m = (j < NCOLS) ? mu_b2[j] : 0.f;
            float b2s = (j < NCOLS) ? sg_b2[j] : 0.f;
            #pragma unroll
            for (int r = 0; r < 4; ++r) {
                float z = 0.f;
                if (j < NCOLS) {
                    float omu = PA[t][(q * 4 + r) * 80 + j];
                    z = (omu + b2m) + ev[nt][r] * (o[nt][r] + b2s);
                }
                z2[(size_t)(rbase + q * 4 + r) * 96 + j] = (__bf16)z;
            }
        }
        #pragma unroll
        for (int r = 0; r < 4; ++r)
            ((unsigned short*)z2)[(size_t)(rbase + q * 4 + r) * 96 + 80 + l16] = 0;
    }
}

// ============================ K3: synthesis ================================
// out = z2 @ Bs. 512 thr = 8 waves = 4 row-tiles x 2 n-halves; 64 rows/block;
// grid 512 -> 2 blocks/CU (LDS 48 KB). Bs streamed in 24 KB double-buffered
// chunks via global_load_lds (6 chunks; de-dupes per-wave L2 re-reads and
// beats the VGPR-load latency ceiling). z2 A-frags read once from L2.
__global__ __launch_bounds__(512, 8) void k_syn(
    const __bf16* __restrict__ z2, const __bf16* __restrict__ Bs,
    float* __restrict__ out)
{
    __shared__ __align__(16) char R[49152];   // Bq[2][24K]
    int tid = threadIdx.x;
    int w = tid >> 6, lane = tid & 63, q = lane >> 4, l16 = lane & 15;
    int t = w >> 1, g = w & 1;
    int rbase = blockIdx.x * 64;

    bf16x8 az[3];
    #pragma unroll
    for (int ks = 0; ks < 3; ++ks)
        az[ks] = *(const bf16x8*)(z2 + (size_t)(rbase + t * 16 + l16) * 96
                                     + ks * 32 + q * 8);

    // stage chunk c: 24 units; unit u -> frag (u<12 ? 12c+u : 72+12c+(u-12))
    #define SYN_STAGE(c, dst)                                                  \
        _Pragma("unroll")                                                      \
        for (int uu = 0; uu < 3; ++uu) {                                       \
            int u = w + uu * 8;                                                \
            int frag = (u < 12) ? (12 * (c) + u) : (72 + 12 * (c) + (u - 12)); \
            __builtin_amdgcn_global_load_lds(                                  \
                (g_u32*)(Bs + (size_t)frag * 512 + lane * 8),                  \
                (l_u32*)((dst) + u * 1024), 16, 0, 0);                         \
        }

    SYN_STAGE(0, R)
    __syncthreads();
    for (int c = 0; c < 6; ++c) {
        int buf = c & 1;
        if (c < 5) SYN_STAGE(c + 1, R + (buf ^ 1) * 24576)
        const char* bb = R + buf * 24576 + g * 12288 + (size_t)lane * 16;
        #pragma unroll
        for (int ntl = 0; ntl < 4; ++ntl) {
            f32x4 oc = {};
            #pragma unroll
            for (int ks = 0; ks < 3; ++ks) {
                bf16x8 b = *(const bf16x8*)(bb + (ntl * 3 + ks) * 1024);
                oc = MFMA16(az[ks], b, oc);
            }
            int nt = g * 24 + 4 * c + ntl;
            #pragma unroll
            for (int r = 0; r < 4; ++r)
                out[(size_t)(rbase + t * 16 + q * 4 + r) * INDIM + nt * 16 + l16]
                    = oc[r];
        }
        if (c < 5) __syncthreads();
    }
    #undef SYN_STAGE
}

extern "C" void kernel_launch(void* const* d_in, const int* in_sizes, int n_in,
                              void* d_out, int out_size, void* d_ws, size_t ws_size,
                              hipStream_t stream)
{
    const float* x     = (const float*)d_in[0];
    const float* eps   = (const float*)d_in[1];
    const int*   idxs  = (const int*)  d_in[2];
    const float* mu_w1 = (const float*)d_in[3];
    const float* mu_b1 = (const float*)d_in[4];
    const float* mu_g  = (const float*)d_in[5];
    const float* mu_be = (const float*)d_in[6];
    const float* mu_w2 = (const float*)d_in[7];
    const float* mu_b2 = (const float*)d_in[8];
    const float* sg_w1 = (const float*)d_in[9];
    const float* sg_b1 = (const float*)d_in[10];
    const float* sg_g  = (const float*)d_in[11];
    const float* sg_be = (const float*)d_in[12];
    const float* sg_w2 = (const float*)d_in[13];
    const float* sg_b2 = (const float*)d_in[14];
    float* out = (float*)d_out;

    char* ws = (char*)d_ws;
    __bf16* BfP = (__bf16*)(ws + OFF_BFP);
    __bf16* W1P = (__bf16*)(ws + OFF_W1P);
    __bf16* W2P = (__bf16*)(ws + OFF_W2P);
    __bf16* BsP = (__bf16*)(ws + OFF_BSP);
    __bf16* Z1  = (__bf16*)(ws + OFF_Z1);
    __bf16* Z2  = (__bf16*)(ws + OFF_Z2);

    hipLaunchKernelGGL(k_prep, dim3(1024), dim3(256), 0, stream,
                       idxs, mu_w1, sg_w1, mu_w2, sg_w2, BfP, W1P, W2P, BsP);
    hipLaunchKernelGGL(k_dft, dim3(NROWS / 64), dim3(512), 0, stream,
                       x, BfP, Z1);
    hipLaunchKernelGGL(k_mlp, dim3(NROWS / 32), dim3(256), 0, stream,
                       Z1, eps, W1P, W2P,
                       mu_b1, mu_g, mu_be, mu_b2,
                       sg_b1, sg_g, sg_be, sg_b2, Z2);
    hipLaunchKernelGGL(k_syn, dim3(NROWS / 64), dim3(512), 0, stream,
                       Z2, BsP, out);
}

// Round 6
// 243.803 us; speedup vs baseline: 1.0365x; 1.0191x over previous
//
#include <hip/hip_runtime.h>
#include <hip/hip_bf16.h>
#include <math.h>

#define INDIM 768
#define NROWS 32768       // 8*4096
#define KSEL  38
#define NCOLS 76
#define HID   256
#define LN_EPS 1e-5f

typedef float  f32x4  __attribute__((ext_vector_type(4)));
typedef __bf16 bf16x8 __attribute__((ext_vector_type(8)));

#define MFMA16(a,b,c) __builtin_amdgcn_mfma_f32_16x16x32_bf16((a),(b),(c),0,0,0)

// ---- workspace: shared matrices pre-packed in MFMA B-fragment order ----
// frag value(lane, j) = M[n = nt*16 + (lane&15)][k = ks*32 + (lane>>4)*8 + j]
// BfP: DFT basis,  frag = kc*5 + nt   (kc 0..23, nt 0..4)   : 120 frags
// W1P: layer1 w,   frag = mlp*48 + nt*3 + ks (nt 0..15)     : 96 frags
// W2P: layer2 w,   frag = mlp*40 + nt*8 + ks (nt 0..4)      : 80 frags
// BsP: synth basis frag = nt*3 + ks  (nt 0..47)             : 144 frags
#define OFF_BFP 0
#define OFF_W1P 122880
#define OFF_W2P 221184
#define OFF_BSP 303104

__global__ void k_prep(const int* __restrict__ idxs,
                       const float* __restrict__ mu_w1, const float* __restrict__ sg_w1,
                       const float* __restrict__ mu_w2, const float* __restrict__ sg_w2,
                       __bf16* __restrict__ BfP, __bf16* __restrict__ W1P,
                       __bf16* __restrict__ W2P, __bf16* __restrict__ BsP)
{
    int tid = blockIdx.x * blockDim.x + threadIdx.x;
    int nth = gridDim.x * blockDim.x;
    const float TH = 6.28318530717958647692f / (float)INDIM;

    for (int e = tid; e < 120 * 512; e += nth) {
        int frag = e >> 9, lane = (e >> 3) & 63, j = e & 7;
        int kc = frag / 5, nt = frag % 5;
        int c = nt * 16 + (lane & 15);
        int k = kc * 32 + ((lane >> 4) << 3) + j;
        float v = 0.f;
        if (c < NCOLS) {
            int cc = (c < KSEL) ? c : c - KSEL;
            int f = idxs[cc];
            int m = (f * k) % INDIM;
            float s, co; sincosf(TH * (float)m, &s, &co);
            v = (c < KSEL) ? co : -s;
        }
        BfP[e] = (__bf16)v;
    }
    for (int e = tid; e < 96 * 512; e += nth) {
        int frag = e >> 9, lane = (e >> 3) & 63, j = e & 7;
        int mlp = frag / 48; int r = frag % 48;
        int nt = r / 3, ks = r % 3;
        int row = nt * 16 + (lane & 15);
        int k = ks * 32 + ((lane >> 4) << 3) + j;
        const float* W = mlp ? sg_w1 : mu_w1;
        W1P[e] = (__bf16)((k < NCOLS) ? W[row * NCOLS + k] : 0.f);
    }
    for (int e = tid; e < 80 * 512; e += nth) {
        int frag = e >> 9, lane = (e >> 3) & 63, j = e & 7;
        int mlp = frag / 40; int r = frag % 40;
        int nt = r / 8, ks = r % 8;
        int row = nt * 16 + (lane & 15);
        int k = ks * 32 + ((lane >> 4) << 3) + j;
        const float* W = mlp ? sg_w2 : mu_w2;
        W2P[e] = (__bf16)((row < NCOLS) ? W[row * HID + k] : 0.f);
    }
    for (int e = tid; e < 144 * 512; e += nth) {
        int frag = e >> 9, lane = (e >> 3) & 63, j = e & 7;
        int nt = frag / 3, ks = frag % 3;
        int n = nt * 16 + (lane & 15);
        int k = ks * 32 + ((lane >> 4) << 3) + j;
        float v = 0.f;
        if (k < NCOLS) {
            int cc = (k < KSEL) ? k : k - KSEL;
            int f = idxs[cc];
            int m = (f * n) % INDIM;
            float s, co; sincosf(TH * (float)m, &s, &co);
            v = ((k < KSEL) ? co : -s) * (2.0f / (float)INDIM);
        }
        BsP[e] = (__bf16)v;
    }
}

// tanh-form gelu (error vs exact ~3e-4 on gelu out -> ~5e-6 on final out)
static __device__ inline float gelu_fast(float v) {
    float u = v * (0.79788456080286535588f + 0.03567740813636141f * v * v);
    return v / (1.f + __expf(-2.f * u));
}

// cooperative async stage: nunits x 1KB units, unit u -> dst + u*1024,
// 16 waves round-robin (u % 16 == w). Global src per-lane (base + lane*16B),
// LDS dst wave-uniform (HW adds lane*16). Zero VGPR, drained by syncthreads.
static __device__ __forceinline__ void stage16(
    const __bf16* __restrict__ src, int nunits, char* dst, int w, int lane)
{
    typedef __attribute__((address_space(1))) const unsigned int g_u32;
    typedef __attribute__((address_space(3))) unsigned int l_u32;
    for (int u = w; u < nunits; u += 16)
        __builtin_amdgcn_global_load_lds((g_u32*)(src + (size_t)u * 512 + lane * 8),
                                         (l_u32*)(dst + u * 1024), 16, 0, 0);
}

// PERSISTENT-TILE fused kernel (R2 structure) + 2-TILE B-REUSE in ph1/ph5:
// 1024 thr = 16 waves, 128 rows/block (8 tiles x 16), grid 256 = 1 block/CU.
// ph1: 16 waves = 4 tile-PAIRS {pr, pr+4} x 4 K-quarters (K=192 each);
//      each B-frag read once per PAIR (was once per tile) -> LDS B-reads
//      960->480 KB; fp32 4-way combine via PA3 overlay (exactly 120 KB).
// ph2/ph3: unchanged pair-split (h[16] AGPR forbids tile-pairing there).
// ph5: 16 waves = 4 tile-pairs x 4 N-quarters -> LDS B-reads 1152->576 KB.
// Total LDS B traffic 3.5 -> 2.4 MB/CU (~-5 us at 85 B/cy) + halved ph1/ph5
// MFMA-adjacent issue. Max-live regs: ph2 (64 AGPR h + ~40 VGPR) -> still
// inside launch_bounds(1024,4)'s 128-reg budget; ph1's ~75 live regs die at B4.
// LDS = R 120K + tbuf 26K = 146.5 KB -> 1 block/CU, 4 waves/SIMD.
__global__ __launch_bounds__(1024, 4) void k_fused(
    const float* __restrict__ x, const float* __restrict__ eps,
    const __bf16* __restrict__ Bf, const __bf16* __restrict__ W1f,
    const __bf16* __restrict__ W2f, const __bf16* __restrict__ Bs,
    const float* __restrict__ mu_b1, const float* __restrict__ mu_g,
    const float* __restrict__ mu_be, const float* __restrict__ mu_b2,
    const float* __restrict__ sg_b1, const float* __restrict__ sg_g,
    const float* __restrict__ sg_be, const float* __restrict__ sg_b2,
    float* __restrict__ out)
{
    __shared__ __align__(16) char   R[122880];       // B region / PA3 / PA / GW
    __shared__ __align__(16) __bf16 tbuf[8][1664];   // per-tile 16x104 transpose buf
    float* PA3 = (float*)R;                          // [3][8][1280] f32 (ph1)
    float* PA  = (float*)R;                          // [8][1280] f32 (ph4)

    int tid = threadIdx.x;
    int w = tid >> 6, lane = tid & 63, q = lane >> 4, l16 = lane & 15;
    // ph1/ph5 mapping: tile pair {pr, pr+4}, quarter kq/nq
    int pr = w >> 2, kq = w & 3;
    int t0 = pr, t1 = pr + 4;
    int rb0 = blockIdx.x * 128 + t0 * 16;
    int rb1 = blockIdx.x * 128 + t1 * 16;
    // ph2..ph4 mapping: single tile t2, mlp p
    int t2 = w >> 1, p = w & 1;
    int rbase2 = blockIdx.x * 128 + t2 * 16;

    // ---------------- Phase 1: DFT, 2 tiles/wave, K-quarter kq ---------------
    f32x4 acc0[5] = {}, acc1[5] = {};
    {
        const float* xr0 = x + (size_t)(rb0 + l16) * INDIM + kq * 192 + q * 8;
        const float* xr1 = xr0 + (size_t)64 * INDIM;
        stage16(Bf, 120, R, w, lane);                 // full DFT basis -> LDS
        __syncthreads();                              // B1: Bf ready
        #pragma unroll
        for (int kk = 0; kk < 6; ++kk) {
            float4 f0 = ((const float4*)(xr0 + kk * 32))[0];
            float4 f1 = ((const float4*)(xr0 + kk * 32))[1];
            float4 g0 = ((const float4*)(xr1 + kk * 32))[0];
            float4 g1 = ((const float4*)(xr1 + kk * 32))[1];
            union { __bf16 h[8]; bf16x8 v; } a0, a1u;
            a0.h[0]=(__bf16)f0.x; a0.h[1]=(__bf16)f0.y; a0.h[2]=(__bf16)f0.z; a0.h[3]=(__bf16)f0.w;
            a0.h[4]=(__bf16)f1.x; a0.h[5]=(__bf16)f1.y; a0.h[6]=(__bf16)f1.z; a0.h[7]=(__bf16)f1.w;
            a1u.h[0]=(__bf16)g0.x; a1u.h[1]=(__bf16)g0.y; a1u.h[2]=(__bf16)g0.z; a1u.h[3]=(__bf16)g0.w;
            a1u.h[4]=(__bf16)g1.x; a1u.h[5]=(__bf16)g1.y; a1u.h[6]=(__bf16)g1.z; a1u.h[7]=(__bf16)g1.w;
            const char* bb = R + (size_t)((kq * 6 + kk) * 5) * 1024 + (size_t)lane * 16;
            #pragma unroll
            for (int nt = 0; nt < 5; ++nt) {
                bf16x8 b = *(const bf16x8*)(bb + nt * 1024);   // read once,
                acc0[nt] = MFMA16(a0.v, b, acc0[nt]);          // used twice
                acc1[nt] = MFMA16(a1u.v, b, acc1[nt]);
            }
        }
    }
    __syncthreads();                                  // B2: Bf dead -> PA3 overlay
    if (kq != 0) {
        int base0 = ((kq - 1) * 8 + t0) * 1280;
        int base1 = ((kq - 1) * 8 + t1) * 1280;
        #pragma unroll
        for (int nt = 0; nt < 5; ++nt)
            #pragma unroll
            for (int r = 0; r < 4; ++r) {
                int i = (q * 4 + r) * 80 + nt * 16 + l16;
                PA3[base0 + i] = acc0[nt][r];
                PA3[base1 + i] = acc1[nt][r];
            }
    }
    __syncthreads();                                  // B3: PA3 ready
    if (kq == 0) {
        #pragma unroll
        for (int nt = 0; nt < 5; ++nt)
            #pragma unroll
            for (int r = 0; r < 4; ++r) {
                int i = (q * 4 + r) * 80 + nt * 16 + l16;
                float v0 = acc0[nt][r] + PA3[t0 * 1280 + i]
                         + PA3[(8 + t0) * 1280 + i] + PA3[(16 + t0) * 1280 + i];
                float v1 = acc1[nt][r] + PA3[t1 * 1280 + i]
                         + PA3[(8 + t1) * 1280 + i] + PA3[(16 + t1) * 1280 + i];
                tbuf[t0][(q * 4 + r) * 104 + nt * 16 + l16] = (__bf16)v0;
                tbuf[t1][(q * 4 + r) * 104 + nt * 16 + l16] = (__bf16)v1;
            }
        #pragma unroll
        for (int r = 0; r < 4; ++r) {
            tbuf[t0][(q * 4 + r) * 104 + 80 + l16] = (__bf16)0.f;
            tbuf[t1][(q * 4 + r) * 104 + 80 + l16] = (__bf16)0.f;
        }
    }
    __syncthreads();                                  // B4: tbuf ready, PA3 dead
    stage16(W1f, 96, R, w, lane);                     // full layer-1 weights -> LDS
    bf16x8 a1[3];
    #pragma unroll
    for (int ks = 0; ks < 3; ++ks)
        a1[ks] = *(const bf16x8*)&tbuf[t2][l16 * 104 + ks * 32 + q * 8];
    __syncthreads();                                  // B5: W1P ready

    // ---------------- Phase 2: this wave's MLP (mlp = p), layer1 -------------
    const float* b1 = p ? sg_b1 : mu_b1;
    const float* g  = p ? sg_g  : mu_g;
    const float* be = p ? sg_be : mu_be;

    f32x4 h[16] = {};
    #pragma unroll
    for (int nt = 0; nt < 16; ++nt)
        #pragma unroll
        for (int ks = 0; ks < 3; ++ks) {
            bf16x8 b = *(const bf16x8*)(R + (size_t)((p * 48 + nt * 3 + ks) * 1024)
                                          + (size_t)lane * 16);
            h[nt] = MFMA16(a1[ks], b, h[nt]);
        }
    float s[4] = {}, ss[4] = {};
    #pragma unroll
    for (int nt = 0; nt < 16; ++nt) {
        float bb = b1[nt * 16 + l16];
        #pragma unroll
        for (int r = 0; r < 4; ++r) {
            float v = h[nt][r] + bb; h[nt][r] = v;
            s[r] += v; ss[r] += v * v;
        }
    }
    #pragma unroll
    for (int off = 1; off < 16; off <<= 1)
        #pragma unroll
        for (int r = 0; r < 4; ++r) {
            s[r] += __shfl_xor(s[r], off); ss[r] += __shfl_xor(ss[r], off);
        }
    float mean[4], rstd[4];
    #pragma unroll
    for (int r = 0; r < 4; ++r) {
        mean[r] = s[r] * (1.f / 256.f);
        rstd[r] = rsqrtf(ss[r] * (1.f / 256.f) - mean[r] * mean[r] + LN_EPS);
    }
    __syncthreads();                                  // B6: W1P dead -> GW overlay ok
    // LN + gelu -> wave-private buffer (stride 136), two K-halves
    __bf16* gw = (__bf16*)R + w * 2176;
    bf16x8 a2[8];
    #pragma unroll
    for (int half = 0; half < 2; ++half) {
        #pragma unroll
        for (int ntl = 0; ntl < 8; ++ntl) {
            int nt = half * 8 + ntl;
            int i = nt * 16 + l16;
            float gv = g[i], bev = be[i];
            #pragma unroll
            for (int r = 0; r < 4; ++r)
                gw[(q * 4 + r) * 136 + ntl * 16 + l16] =
                    (__bf16)gelu_fast((h[nt][r] - mean[r]) * rstd[r] * gv + bev);
        }
        #pragma unroll
        for (int ks = 0; ks < 4; ++ks)
            a2[half * 4 + ks] = *(const bf16x8*)&gw[l16 * 136 + ks * 32 + q * 8];
    }
    __syncthreads();                                  // B7: GW dead
    stage16(W2f, 80, R, w, lane);                     // full layer-2 weights -> LDS
    __syncthreads();                                  // B8: W2P ready

    // ---------------- Phase 3: layer2 (this wave's MLP) ----------------------
    f32x4 o[5] = {};
    #pragma unroll
    for (int nt = 0; nt < 5; ++nt)
        #pragma unroll
        for (int ks = 0; ks < 8; ++ks) {
            bf16x8 b = *(const bf16x8*)(R + (size_t)((p * 40 + nt * 8 + ks) * 1024)
                                          + (size_t)lane * 16);
            o[nt] = MFMA16(a2[ks], b, o[nt]);
        }
    __syncthreads();                                  // B9: W2P dead -> PA overlay ok

    // ---------------- Phase 4: z = (mu+b2m) + eps*(sg+b2s) -------------------
    float ev[5][4];
    if (p == 0) {
        // publish o_mu
        #pragma unroll
        for (int nt = 0; nt < 5; ++nt)
            #pragma unroll
            for (int r = 0; r < 4; ++r)
                PA[t2 * 1280 + (q * 4 + r) * 80 + nt * 16 + l16] = o[nt][r];
    } else {
        // prefetch eps
        #pragma unroll
        for (int nt = 0; nt < 5; ++nt) {
            int j = nt * 16 + l16;
            #pragma unroll
            for (int r = 0; r < 4; ++r)
                ev[nt][r] = (j < NCOLS)
                    ? eps[(size_t)(rbase2 + q * 4 + r) * NCOLS + j] : 0.f;
        }
    }
    __syncthreads();                                  // B10: PA(mu) ready
    if (p == 1) {
        #pragma unroll
        for (int nt = 0; nt < 5; ++nt) {
            int j = nt * 16 + l16;
            float b2m = (j < NCOLS) ? mu_b2[j] : 0.f;
            float b2s = (j < NCOLS) ? sg_b2[j] : 0.f;
            #pragma unroll
            for (int r = 0; r < 4; ++r) {
                float z = 0.f;
                if (j < NCOLS) {
                    float omu = PA[t2 * 1280 + (q * 4 + r) * 80 + j];
                    z = (omu + b2m) + ev[nt][r] * (o[nt][r] + b2s);
                }
                tbuf[t2][(q * 4 + r) * 104 + j] = (__bf16)z;
            }
        }
        #pragma unroll
        for (int r = 0; r < 4; ++r)
            tbuf[t2][(q * 4 + r) * 104 + 80 + l16] = (__bf16)0.f;
    }
    __syncthreads();                                  // B11: z ready, PA dead
    stage16(Bs, 72, R, w, lane);                      // synth basis half 0 -> LDS
    bf16x8 az0[3], az1[3];
    #pragma unroll
    for (int ks = 0; ks < 3; ++ks) {
        az0[ks] = *(const bf16x8*)&tbuf[t0][l16 * 104 + ks * 32 + q * 8];
        az1[ks] = *(const bf16x8*)&tbuf[t1][l16 * 104 + ks * 32 + q * 8];
    }
    __syncthreads();                                  // B12: half 0 ready

    // ---------------- Phase 5: synthesis, 2 tiles/wave, N-quarter ------------
    // per half: wave covers nt-slice [nq*6, nq*6+6) of 24; B-frag read once,
    // used for both row tiles.
    #pragma unroll
    for (int half = 0; half < 2; ++half) {
        if (half == 1) {
            __syncthreads();                          // B13: half 0 dead
            stage16(Bs + (size_t)72 * 512, 72, R, w, lane);
            __syncthreads();                          // B14: half 1 ready
        }
        #pragma unroll 3
        for (int c = 0; c < 6; ++c) {
            int ntl = kq * 6 + c;                     // frag-local n-tile in half
            int ntg = half * 24 + ntl;                // global n-tile
            f32x4 oc0 = {}, oc1 = {};
            #pragma unroll
            for (int ks = 0; ks < 3; ++ks) {
                bf16x8 b = *(const bf16x8*)(R + (size_t)((ntl * 3 + ks) * 1024)
                                              + (size_t)lane * 16);
                oc0 = MFMA16(az0[ks], b, oc0);
                oc1 = MFMA16(az1[ks], b, oc1);
            }
            #pragma unroll
            for (int r = 0; r < 4; ++r) {
                out[(size_t)(rb0 + q * 4 + r) * INDIM + ntg * 16 + l16] = oc0[r];
                out[(size_t)(rb1 + q * 4 + r) * INDIM + ntg * 16 + l16] = oc1[r];
            }
        }
    }
}

extern "C" void kernel_launch(void* const* d_in, const int* in_sizes, int n_in,
                              void* d_out, int out_size, void* d_ws, size_t ws_size,
                              hipStream_t stream)
{
    const float* x     = (const float*)d_in[0];
    const float* eps   = (const float*)d_in[1];
    const int*   idxs  = (const int*)  d_in[2];
    const float* mu_w1 = (const float*)d_in[3];
    const float* mu_b1 = (const float*)d_in[4];
    const float* mu_g  = (const float*)d_in[5];
    const float* mu_be = (const float*)d_in[6];
    const float* mu_w2 = (const float*)d_in[7];
    const float* mu_b2 = (const float*)d_in[8];
    const float* sg_w1 = (const float*)d_in[9];
    const float* sg_b1 = (const float*)d_in[10];
    const float* sg_g  = (const float*)d_in[11];
    const float* sg_be = (const float*)d_in[12];
    const float* sg_w2 = (const float*)d_in[13];
    const float* sg_b2 = (const float*)d_in[14];
    float* out = (float*)d_out;

    char* ws = (char*)d_ws;
    __bf16* BfP = (__bf16*)(ws + OFF_BFP);
    __bf16* W1P = (__bf16*)(ws + OFF_W1P);
    __bf16* W2P = (__bf16*)(ws + OFF_W2P);
    __bf16* BsP = (__bf16*)(ws + OFF_BSP);

    hipLaunchKernelGGL(k_prep, dim3(1024), dim3(256), 0, stream,
                       idxs, mu_w1, sg_w1, mu_w2, sg_w2, BfP, W1P, W2P, BsP);
    hipLaunchKernelGGL(k_fused, dim3(NROWS / 128), dim3(1024), 0, stream,
                       x, eps, BfP, W1P, W2P, BsP,
                       mu_b1, mu_g, mu_be, mu_b2,
                       sg_b1, sg_g, sg_be, sg_b2, out);
}

// Round 7
// 238.011 us; speedup vs baseline: 1.0617x; 1.0243x over previous
//
#include <hip/hip_runtime.h>
#include <hip/hip_bf16.h>
#include <math.h>

#define INDIM 768
#define NROWS 32768       // 8*4096
#define KSEL  38
#define NCOLS 76
#define HID   256
#define LN_EPS 1e-5f

typedef float  f32x4  __attribute__((ext_vector_type(4)));
typedef __bf16 bf16x8 __attribute__((ext_vector_type(8)));

#define MFMA16(a,b,c) __builtin_amdgcn_mfma_f32_16x16x32_bf16((a),(b),(c),0,0,0)

// ---- workspace: shared matrices pre-packed in MFMA B-fragment order ----
// frag value(lane, j) = M[n = nt*16 + (lane&15)][k = ks*32 + (lane>>4)*8 + j]
// BfP: DFT basis,  frag = kc*5 + nt   (kc 0..23, nt 0..4)   : 120 frags
// W1P: layer1 w,   frag = mlp*48 + nt*3 + ks (nt 0..15)     : 96 frags
// W2P: layer2 w,   frag = mlp*40 + nt*8 + ks (nt 0..4)      : 80 frags
// BsP: synth basis frag = nt*3 + ks  (nt 0..47)             : 144 frags
#define OFF_BFP 0
#define OFF_W1P 122880
#define OFF_W2P 221184
#define OFF_BSP 303104

__global__ void k_prep(const int* __restrict__ idxs,
                       const float* __restrict__ mu_w1, const float* __restrict__ sg_w1,
                       const float* __restrict__ mu_w2, const float* __restrict__ sg_w2,
                       __bf16* __restrict__ BfP, __bf16* __restrict__ W1P,
                       __bf16* __restrict__ W2P, __bf16* __restrict__ BsP)
{
    int tid = blockIdx.x * blockDim.x + threadIdx.x;
    int nth = gridDim.x * blockDim.x;
    const float TH = 6.28318530717958647692f / (float)INDIM;

    for (int e = tid; e < 120 * 512; e += nth) {
        int frag = e >> 9, lane = (e >> 3) & 63, j = e & 7;
        int kc = frag / 5, nt = frag % 5;
        int c = nt * 16 + (lane & 15);
        int k = kc * 32 + ((lane >> 4) << 3) + j;
        float v = 0.f;
        if (c < NCOLS) {
            int cc = (c < KSEL) ? c : c - KSEL;
            int f = idxs[cc];
            int m = (f * k) % INDIM;
            float s, co; sincosf(TH * (float)m, &s, &co);
            v = (c < KSEL) ? co : -s;
        }
        BfP[e] = (__bf16)v;
    }
    for (int e = tid; e < 96 * 512; e += nth) {
        int frag = e >> 9, lane = (e >> 3) & 63, j = e & 7;
        int mlp = frag / 48; int r = frag % 48;
        int nt = r / 3, ks = r % 3;
        int row = nt * 16 + (lane & 15);
        int k = ks * 32 + ((lane >> 4) << 3) + j;
        const float* W = mlp ? sg_w1 : mu_w1;
        W1P[e] = (__bf16)((k < NCOLS) ? W[row * NCOLS + k] : 0.f);
    }
    for (int e = tid; e < 80 * 512; e += nth) {
        int frag = e >> 9, lane = (e >> 3) & 63, j = e & 7;
        int mlp = frag / 40; int r = frag % 40;
        int nt = r / 8, ks = r % 8;
        int row = nt * 16 + (lane & 15);
        int k = ks * 32 + ((lane >> 4) << 3) + j;
        const float* W = mlp ? sg_w2 : mu_w2;
        W2P[e] = (__bf16)((row < NCOLS) ? W[row * HID + k] : 0.f);
    }
    for (int e = tid; e < 144 * 512; e += nth) {
        int frag = e >> 9, lane = (e >> 3) & 63, j = e & 7;
        int nt = frag / 3, ks = frag % 3;
        int n = nt * 16 + (lane & 15);
        int k = ks * 32 + ((lane >> 4) << 3) + j;
        float v = 0.f;
        if (k < NCOLS) {
            int cc = (k < KSEL) ? k : k - KSEL;
            int f = idxs[cc];
            int m = (f * n) % INDIM;
            float s, co; sincosf(TH * (float)m, &s, &co);
            v = ((k < KSEL) ? co : -s) * (2.0f / (float)INDIM);
        }
        BsP[e] = (__bf16)v;
    }
}

// tanh-form gelu (error vs exact ~3e-4 on gelu out -> ~5e-6 on final out)
static __device__ inline float gelu_fast(float v) {
    float u = v * (0.79788456080286535588f + 0.03567740813636141f * v * v);
    return v / (1.f + __expf(-2.f * u));
}

// cooperative async stage: nunits x 1KB units, unit u -> dst + u*1024,
// 16 waves round-robin (u % 16 == w). Global src per-lane (base + lane*16B),
// LDS dst wave-uniform (HW adds lane*16). Zero VGPR; a wave's issued loads
// are drained by the wave's own vmcnt(0) at the NEXT __syncthreads, so data
// is globally visible after that barrier.
static __device__ __forceinline__ void stage16(
    const __bf16* __restrict__ src, int nunits, char* dst, int w, int lane)
{
    typedef __attribute__((address_space(1))) const unsigned int g_u32;
    typedef __attribute__((address_space(3))) unsigned int l_u32;
    for (int u = w; u < nunits; u += 16)
        __builtin_amdgcn_global_load_lds((g_u32*)(src + (size_t)u * 512 + lane * 8),
                                         (l_u32*)(dst + u * 1024), 16, 0, 0);
}

// PERSISTENT-TILE fused kernel (R2 structure) + EARLY-STAGE region schedule:
// 1024 thr = 16 waves, 128 rows/block (8 tiles x 16), grid 256 = 1 block/CU.
// R2's serial cost: stage drains at B5/B8/B12/B14 (96/80/72/72 KB) with no
// covering work. Fix: PA overlay moved to TOP 40K of R so each next-phase
// matrix begins staging as soon as its region is dead, several barriers
// before use:
//   W1 80K after B3 (under combine)  + 16K after B4   -> B5 exposes 16K
//   W2 50K after B6 (under gelu)     + 30K after B7   -> B8 exposes 30K
//   Bs-h0 72K after B9 (under ph4)                    -> B12 DELETED
//   Bs-h1 48K after B11 (under ph5-h0) + 24K after B13-> B14 exposes 24K
// Region liveness verified pairwise; every overlay reuse is barrier-separated.
// LDS = R 120K + tbuf 26K = 146.5 KB -> 1 block/CU, 4 waves/SIMD (reg-pinned:
// ph2's h[16]=64 AGPR + ~40 VGPR; do NOT add registers).
__global__ __launch_bounds__(1024, 4) void k_fused(
    const float* __restrict__ x, const float* __restrict__ eps,
    const __bf16* __restrict__ Bf, const __bf16* __restrict__ W1f,
    const __bf16* __restrict__ W2f, const __bf16* __restrict__ Bs,
    const float* __restrict__ mu_b1, const float* __restrict__ mu_g,
    const float* __restrict__ mu_be, const float* __restrict__ mu_b2,
    const float* __restrict__ sg_b1, const float* __restrict__ sg_g,
    const float* __restrict__ sg_be, const float* __restrict__ sg_b2,
    float* __restrict__ out)
{
    __shared__ __align__(16) char   R[122880];       // B region / PA / GW overlay
    __shared__ __align__(16) __bf16 tbuf[8][1664];   // per-tile 16x104 transpose buf
    float* PA = (float*)(R + 81920);                 // [8][1280] f32, TOP of R

    int tid = threadIdx.x;
    int w = tid >> 6, lane = tid & 63, q = lane >> 4, l16 = lane & 15;
    int t = w >> 1, p = w & 1;
    int rbase = blockIdx.x * 128 + t * 16;

    // ---------------- Phase 1: DFT, this wave does K-half p (12 kc) ----------
    f32x4 acc[5] = {};
    {
        const float* xrow = x + (size_t)(rbase + l16) * INDIM + p * 384 + q * 8;
        stage16(Bf, 120, R, w, lane);                 // full DFT basis -> LDS
        float4 f0 = ((const float4*)xrow)[0];
        float4 f1 = ((const float4*)xrow)[1];
        __syncthreads();                              // B1: Bf ready
        #pragma unroll
        for (int kk = 0; kk < 12; ++kk) {
            float4 n0, n1;
            if (kk < 11) {                            // x prefetch, 1 iter ahead
                n0 = ((const float4*)(xrow + (kk + 1) * 32))[0];
                n1 = ((const float4*)(xrow + (kk + 1) * 32))[1];
            }
            union { __bf16 h[8]; bf16x8 v; } a;
            a.h[0]=(__bf16)f0.x; a.h[1]=(__bf16)f0.y; a.h[2]=(__bf16)f0.z; a.h[3]=(__bf16)f0.w;
            a.h[4]=(__bf16)f1.x; a.h[5]=(__bf16)f1.y; a.h[6]=(__bf16)f1.z; a.h[7]=(__bf16)f1.w;
            const char* bb = R + (size_t)((p * 12 + kk) * 5) * 1024 + (size_t)lane * 16;
            #pragma unroll
            for (int nt = 0; nt < 5; ++nt) {
                bf16x8 b = *(const bf16x8*)(bb + nt * 1024);
                acc[nt] = MFMA16(a.v, b, acc[nt]);
            }
            if (kk < 11) { f0 = n0; f1 = n1; }
        }
    }
    __syncthreads();                                  // B2: Bf dead everywhere
    // combine halves (fp32) via PA-top + transpose to A-layout in tbuf[t]
    if (p == 1) {
        #pragma unroll
        for (int nt = 0; nt < 5; ++nt)
            #pragma unroll
            for (int r = 0; r < 4; ++r)
                PA[t * 1280 + (q * 4 + r) * 80 + nt * 16 + l16] = acc[nt][r];
    }
    __syncthreads();                                  // B3: PA ready
    // EARLY: W1 frags 0..79 -> R[0..80K) (disjoint from PA top 40K); drains
    // under the combine work below, fully arrived at B4.
    stage16(W1f, 80, R, w, lane);
    if (p == 0) {
        #pragma unroll
        for (int nt = 0; nt < 5; ++nt)
            #pragma unroll
            for (int r = 0; r < 4; ++r) {
                float v = acc[nt][r] + PA[t * 1280 + (q * 4 + r) * 80 + nt * 16 + l16];
                tbuf[t][(q * 4 + r) * 104 + nt * 16 + l16] = (__bf16)v;
            }
        #pragma unroll
        for (int r = 0; r < 4; ++r)
            tbuf[t][(q * 4 + r) * 104 + 80 + l16] = (__bf16)0.f;
    }
    __syncthreads();                                  // B4: tbuf ready, PA dead
    // tail: W1 frags 80..95 -> R[80K..96K) (natural offsets, contiguous map)
    stage16(W1f + (size_t)80 * 512, 16, R + 81920, w, lane);
    bf16x8 a1[3];
    #pragma unroll
    for (int ks = 0; ks < 3; ++ks)
        a1[ks] = *(const bf16x8*)&tbuf[t][l16 * 104 + ks * 32 + q * 8];
    __syncthreads();                                  // B5: W1 ready (16K exposed)

    // ---------------- Phase 2: this wave's MLP (mlp = p), layer1 -------------
    const float* b1 = p ? sg_b1 : mu_b1;
    const float* g  = p ? sg_g  : mu_g;
    const float* be = p ? sg_be : mu_be;

    f32x4 h[16] = {};
    #pragma unroll
    for (int nt = 0; nt < 16; ++nt)
        #pragma unroll
        for (int ks = 0; ks < 3; ++ks) {
            bf16x8 b = *(const bf16x8*)(R + (size_t)((p * 48 + nt * 3 + ks) * 1024)
                                          + (size_t)lane * 16);
            h[nt] = MFMA16(a1[ks], b, h[nt]);
        }
    float s[4] = {}, ss[4] = {};
    #pragma unroll
    for (int nt = 0; nt < 16; ++nt) {
        float bb = b1[nt * 16 + l16];
        #pragma unroll
        for (int r = 0; r < 4; ++r) {
            float v = h[nt][r] + bb; h[nt][r] = v;
            s[r] += v; ss[r] += v * v;
        }
    }
    #pragma unroll
    for (int off = 1; off < 16; off <<= 1)
        #pragma unroll
        for (int r = 0; r < 4; ++r) {
            s[r] += __shfl_xor(s[r], off); ss[r] += __shfl_xor(ss[r], off);
        }
    float mean[4], rstd[4];
    #pragma unroll
    for (int r = 0; r < 4; ++r) {
        mean[r] = s[r] * (1.f / 256.f);
        rstd[r] = rsqrtf(ss[r] * (1.f / 256.f) - mean[r] * mean[r] + LN_EPS);
    }
    __syncthreads();                                  // B6: W1 dead -> GW overlay ok
    // EARLY: W2 frags 0..25 -> R+70K..96K and frags 26..49 -> R+96K..120K
    // (both regions dead: W1 frags 70..95 / PA-tail; GW below uses [0..68K)).
    stage16(W2f, 26, R + 71680, w, lane);
    stage16(W2f + (size_t)26 * 512, 24, R + 98304, w, lane);
    // LN + gelu -> wave-private buffer (stride 136), two K-halves
    __bf16* gw = (__bf16*)R + w * 2176;
    bf16x8 a2[8];
    #pragma unroll
    for (int half = 0; half < 2; ++half) {
        #pragma unroll
        for (int ntl = 0; ntl < 8; ++ntl) {
            int nt = half * 8 + ntl;
            int i = nt * 16 + l16;
            float gv = g[i], bev = be[i];
            #pragma unroll
            for (int r = 0; r < 4; ++r)
                gw[(q * 4 + r) * 136 + ntl * 16 + l16] =
                    (__bf16)gelu_fast((h[nt][r] - mean[r]) * rstd[r] * gv + bev);
        }
        #pragma unroll
        for (int ks = 0; ks < 4; ++ks)
            a2[half * 4 + ks] = *(const bf16x8*)&gw[l16 * 136 + ks * 32 + q * 8];
    }
    __syncthreads();                                  // B7: GW dead, W2 p1/p2 ready
    stage16(W2f + (size_t)50 * 512, 30, R, w, lane);  // W2 frags 50..79 -> R[0..30K)
    __syncthreads();                                  // B8: W2 ready (30K exposed)

    // ---------------- Phase 3: layer2 (this wave's MLP) ----------------------
    // frag f = p*40 + nt*8 + ks lives in: f<26 -> R+70K+f*1K;
    // f<50 -> R+96K+(f-26)*1K; else R+(f-50)*1K  (compile-time folded)
    f32x4 o[5] = {};
    #pragma unroll
    for (int nt = 0; nt < 5; ++nt)
        #pragma unroll
        for (int ks = 0; ks < 8; ++ks) {
            int f = p * 40 + nt * 8 + ks;
            const char* base = (f < 26) ? (R + 71680 + f * 1024)
                             : (f < 50) ? (R + 98304 + (f - 26) * 1024)
                                        : (R + (f - 50) * 1024);
            bf16x8 b = *(const bf16x8*)(base + (size_t)lane * 16);
            o[nt] = MFMA16(a2[ks], b, o[nt]);
        }
    __syncthreads();                                  // B9: W2 dead -> PA/Bs ok

    // ---------------- Phase 4: z = (mu+b2m) + eps*(sg+b2s) -------------------
    // EARLY: Bs half0 (frags 0..71) -> R[0..72K); drains under ph4, ready B10.
    stage16(Bs, 72, R, w, lane);
    float ev[5][4];
    if (p == 0) {
        // publish o_mu to PA-top (disjoint from Bs staging region)
        #pragma unroll
        for (int nt = 0; nt < 5; ++nt)
            #pragma unroll
            for (int r = 0; r < 4; ++r)
                PA[t * 1280 + (q * 4 + r) * 80 + nt * 16 + l16] = o[nt][r];
    } else {
        // prefetch eps
        #pragma unroll
        for (int nt = 0; nt < 5; ++nt) {
            int j = nt * 16 + l16;
            #pragma unroll
            for (int r = 0; r < 4; ++r)
                ev[nt][r] = (j < NCOLS)
                    ? eps[(size_t)(rbase + q * 4 + r) * NCOLS + j] : 0.f;
        }
    }
    __syncthreads();                                  // B10: PA(mu) + Bs-h0 ready
    if (p == 1) {
        #pragma unroll
        for (int nt = 0; nt < 5; ++nt) {
            int j = nt * 16 + l16;
            float b2m = (j < NCOLS) ? mu_b2[j] : 0.f;
            float b2s = (j < NCOLS) ? sg_b2[j] : 0.f;
            #pragma unroll
            for (int r = 0; r < 4; ++r) {
                float z = 0.f;
                if (j < NCOLS) {
                    float omu = PA[t * 1280 + (q * 4 + r) * 80 + j];
                    z = (omu + b2m) + ev[nt][r] * (o[nt][r] + b2s);
                }
                tbuf[t][(q * 4 + r) * 104 + j] = (__bf16)z;
            }
        }
        #pragma unroll
        for (int r = 0; r < 4; ++r)
            tbuf[t][(q * 4 + r) * 104 + 80 + l16] = (__bf16)0.f;
    }
    __syncthreads();                                  // B11: z ready, PA dead
    // EARLY: Bs half1 part A (frags 72..119) -> R[72K..120K) (PA + slack dead);
    // drains under ph5-half0 compute, ready at B13.
    stage16(Bs + (size_t)72 * 512, 48, R + 73728, w, lane);
    bf16x8 az[3];
    #pragma unroll
    for (int ks = 0; ks < 3; ++ks)
        az[ks] = *(const bf16x8*)&tbuf[t][l16 * 104 + ks * 32 + q * 8];
    // (no B12: Bs-h0 was drained by B10/B11; az reads need only B11)

    // ---------------- Phase 5: synthesis, 2 halves x 12 n-tiles/wave ---------
    #pragma unroll
    for (int half = 0; half < 2; ++half) {
        if (half == 1) {
            __syncthreads();                          // B13: half0 region dead
            stage16(Bs + (size_t)120 * 512, 24, R, w, lane);  // frags 120..143
            __syncthreads();                          // B14: h1 ready (24K exposed)
        }
        #pragma unroll 4
        for (int c = 0; c < 12; ++c) {
            int ntl = p * 12 + c;                     // frag-local n-tile in half
            int nt  = half * 24 + ntl;                // global n-tile
            f32x4 oc = {};
            #pragma unroll
            for (int ks = 0; ks < 3; ++ks) {
                int idx = ntl * 3 + ks;               // 0..71 within half
                const char* base;
                if (half == 0)       base = R + idx * 1024;
                else if (idx < 48)   base = R + 73728 + idx * 1024;   // frags 72..119
                else                 base = R + (idx - 48) * 1024;    // frags 120..143
                bf16x8 b = *(const bf16x8*)(base + (size_t)lane * 16);
                oc = MFMA16(az[ks], b, oc);
            }
            #pragma unroll
            for (int r = 0; r < 4; ++r)
                out[(size_t)(rbase + q * 4 + r) * INDIM + nt * 16 + l16] = oc[r];
        }
    }
}

extern "C" void kernel_launch(void* const* d_in, const int* in_sizes, int n_in,
                              void* d_out, int out_size, void* d_ws, size_t ws_size,
                              hipStream_t stream)
{
    const float* x     = (const float*)d_in[0];
    const float* eps   = (const float*)d_in[1];
    const int*   idxs  = (const int*)  d_in[2];
    const float* mu_w1 = (const float*)d_in[3];
    const float* mu_b1 = (const float*)d_in[4];
    const float* mu_g  = (const float*)d_in[5];
    const float* mu_be = (const float*)d_in[6];
    const float* mu_w2 = (const float*)d_in[7];
    const float* mu_b2 = (const float*)d_in[8];
    const float* sg_w1 = (const float*)d_in[9];
    const float* sg_b1 = (const float*)d_in[10];
    const float* sg_g  = (const float*)d_in[11];
    const float* sg_be = (const float*)d_in[12];
    const float* sg_w2 = (const float*)d_in[13];
    const float* sg_b2 = (const float*)d_in[14];
    float* out = (float*)d_out;

    char* ws = (char*)d_ws;
    __bf16* BfP = (__bf16*)(ws + OFF_BFP);
    __bf16* W1P = (__bf16*)(ws + OFF_W1P);
    __bf16* W2P = (__bf16*)(ws + OFF_W2P);
    __bf16* BsP = (__bf16*)(ws + OFF_BSP);

    hipLaunchKernelGGL(k_prep, dim3(1024), dim3(256), 0, stream,
                       idxs, mu_w1, sg_w1, mu_w2, sg_w2, BfP, W1P, W2P, BsP);
    hipLaunchKernelGGL(k_fused, dim3(NROWS / 128), dim3(1024), 0, stream,
                       x, eps, BfP, W1P, W2P, BsP,
                       mu_b1, mu_g, mu_be, mu_b2,
                       sg_b1, sg_g, sg_be, sg_b2, out);
}